// Round 1
// baseline (477.182 us; speedup 1.0000x reference)
//
#include <hip/hip_runtime.h>

#define BATCH   64
#define HW      512
#define PS      8
#define HPC     64          // patches per side
#define NPATCH  4096
#define SS      64          // source patch size == target patch size
#define ROWPAD  68          // LDS row stride in floats (68*4B = 272B, 16B-aligned, breaks bank alias)

__global__ __launch_bounds__(256, 4) void axonal_kernel(
    const float* __restrict__ src,
    const float* __restrict__ tr,
    const float* __restrict__ gates,
    const float* __restrict__ biases,
    float* __restrict__ out)
{
    // XCD-aware swizzle: give each of the 8 XCDs a contiguous chunk of patches
    // so adjacent pw (sharing 64B src/out cache lines) stay in one L2. 4096%8==0 -> bijective.
    const int bid = blockIdx.x;
    const int p   = (bid & 7) * (NPATCH / 8) + (bid >> 3);
    const int ph  = p >> 6;
    const int pw  = p & 63;
    const int tid  = threadIdx.x;       // 0..255
    const int w    = tid >> 6;          // wave 0..3
    const int lane = tid & 63;          // 0..63  (= output element t)

    __shared__ __align__(16) float pbuf[BATCH * ROWPAD];  // all 64 patches, [64][68]
    __shared__ float smask[BATCH];                        // per-batch patch sum

    // ---- transform row t = lane into registers (each wave loads all 64 rows; L2 absorbs)
    float trow[64];
    {
        const float4* tp = reinterpret_cast<const float4*>(
            tr + ((size_t)p * SS + lane) * SS);
        #pragma unroll
        for (int k = 0; k < 16; ++k) {
            const float4 v = tp[k];
            trow[4*k+0] = v.x; trow[4*k+1] = v.y;
            trow[4*k+2] = v.z; trow[4*k+3] = v.w;
        }
    }

    // ---- phase 1: stage all 64 batches' patches into LDS (float4 loads, 32B segments)
    {
        const int slot = tid >> 4;      // 0..15 : batch sub-slot
        const int m    = tid & 15;      // 0..15 : quad index within patch
        const int i    = m >> 1;        // patch row 0..7
        const int j4   = (m & 1) * 4;   // col quad 0 or 4
        const float* sp = src + (size_t)(ph*PS + i) * HW + pw*PS + j4;
        #pragma unroll
        for (int it = 0; it < 4; ++it) {
            const int b = it*16 + slot;
            const float4 v = *reinterpret_cast<const float4*>(sp + (size_t)b*HW*HW);
            *reinterpret_cast<float4*>(&pbuf[b*ROWPAD + m*4]) = v;
        }
    }
    __syncthreads();

    // ---- row sums (activity mask) for this wave's 16 batches: 4 lanes per row
    {
        const int bl   = lane >> 2;     // 0..15
        const int part = lane & 3;      // 0..3
        const int b    = w*16 + bl;
        float s0 = 0.f;
        #pragma unroll
        for (int c = 0; c < 4; ++c) {
            const float4 v = *reinterpret_cast<const float4*>(
                &pbuf[b*ROWPAD + (part*4 + c)*4]);
            s0 += (v.x + v.y) + (v.z + v.w);
        }
        s0 += __shfl_xor(s0, 1);
        s0 += __shfl_xor(s0, 2);
        if (part == 0) smask[b] = s0;
        // wave w wrote only its own rows' masks -> no extra barrier needed
    }

    const float g  = gates[p];
    const float bi = biases[p];
    const int ti = lane >> 3;
    const int tj = lane & 7;
    float* op = out + (size_t)(ph*PS + ti) * HW + pw*PS + tj;

    // ---- phase 2: 16 batches per wave; per batch: 16 uniform b128 broadcasts + 64 FMA
    #pragma unroll 2
    for (int bl = 0; bl < 16; ++bl) {
        const int b = w*16 + bl;
        const float* prow = &pbuf[b*ROWPAD];
        float acc = 0.f;
        #pragma unroll
        for (int q = 0; q < 16; ++q) {
            const float4 v = *reinterpret_cast<const float4*>(prow + q*4);
            acc = fmaf(trow[4*q+0], v.x, acc);
            acc = fmaf(trow[4*q+1], v.y, acc);
            acc = fmaf(trow[4*q+2], v.z, acc);
            acc = fmaf(trow[4*q+3], v.w, acc);
        }
        const float mk = smask[b] > 0.f ? 1.f : 0.f;
        op[(size_t)b * HW * HW] = (acc * g + bi) * mk;
    }
}

extern "C" void kernel_launch(void* const* d_in, const int* in_sizes, int n_in,
                              void* d_out, int out_size, void* d_ws, size_t ws_size,
                              hipStream_t stream) {
    const float* src    = (const float*)d_in[0];
    const float* tr     = (const float*)d_in[1];
    const float* gates  = (const float*)d_in[2];
    const float* biases = (const float*)d_in[3];
    float* out = (float*)d_out;

    dim3 grid(NPATCH);
    dim3 block(256);
    hipLaunchKernelGGL(axonal_kernel, grid, block, 0, stream,
                       src, tr, gates, biases, out);
}

// Round 2
// 130.697 us; speedup vs baseline: 3.6511x; 3.6511x over previous
//
#include <hip/hip_runtime.h>

#define HW   512
#define NB   64          // batches
#define SROW 68          // sbuf per-patch stride (floats); 272B, 16B-aligned
#define OROW 72          // obuf row stride (floats); 2-way banks max

__global__ __launch_bounds__(512, 2) void axonal_kernel(
    const float* __restrict__ src,
    const float* __restrict__ tr,
    const float* __restrict__ gates,
    const float* __restrict__ biases,
    float* __restrict__ out)
{
    const int gi   = blockIdx.x;     // 0..511
    const int ph   = gi >> 3;        // patch row 0..63
    const int pwg  = gi & 7;         // group of 8 adjacent pw
    const int tid  = threadIdx.x;    // 0..511
    const int w    = tid >> 6;       // patch within group (= wave) 0..7
    const int lane = tid & 63;       // output row t

    const int p = (ph << 6) + (pwg << 3) + w;

    __shared__ __align__(16) float sbuf[2][8 * SROW];  // [dbuf][patch][64]
    __shared__ __align__(16) float obuf[8 * OROW];     // [out row][64 cols]

    // ---- transform row t = lane for patch p, once, into registers.
    // Block reads a contiguous, aligned 128KB region; every tr byte read exactly once chip-wide.
    float trow[64];
    {
        const float4* tp = reinterpret_cast<const float4*>(tr + ((size_t)p * 64 + lane) * 64);
        #pragma unroll
        for (int k = 0; k < 16; ++k) {
            float4 v = tp[k];
            trow[4*k+0] = v.x; trow[4*k+1] = v.y;
            trow[4*k+2] = v.z; trow[4*k+3] = v.w;
        }
    }
    const float g  = gates[p];
    const float bi = biases[p];

    // ---- stager mapping: threads 0..127 move one float4 per batch.
    // Per wave instruction: 4 rows x 256B contiguous aligned segments.
    const bool stager = (tid < 128);
    const int si = tid >> 4;                 // band row 0..7
    const int sc = (tid & 15) << 2;          // col 0..60 (float4 granule)
    const int sq = sc >> 3;                  // patch the float4 belongs to
    const int sd = sc & 7;                   // 0 or 4 within patch row
    const size_t sbase = (size_t)((ph << 3) + si) * HW + (pwg << 6) + sc;
    const int sdst = sq * SROW + (si << 3) + sd;

    if (stager) {
        float4 v = *reinterpret_cast<const float4*>(src + sbase);
        *reinterpret_cast<float4*>(&sbuf[0][sdst]) = v;
    }
    __syncthreads();

    float* obase = out + (size_t)(ph << 3) * HW + (pwg << 6);
    const int orow = w;       // wave writes one contiguous 256B row segment
    const int ocol = lane;

    for (int b = 0; b < NB; ++b) {
        // issue next batch's loads early (T14): latency hides under compute
        float4 nv;
        if (stager && (b + 1 < NB))
            nv = *reinterpret_cast<const float4*>(src + (size_t)(b + 1) * HW * HW + sbase);

        // ---- dot(trow, patch) : 16 uniform b128 broadcasts + 64 FMA (4 indep chains)
        const float4* sp = reinterpret_cast<const float4*>(&sbuf[b & 1][w * SROW]);
        float a0 = 0.f, a1 = 0.f, a2 = 0.f, a3 = 0.f;
        float s0 = 0.f, s1 = 0.f, s2 = 0.f, s3 = 0.f;
        #pragma unroll
        for (int k = 0; k < 16; ++k) {
            float4 v = sp[k];
            a0 = fmaf(trow[4*k+0], v.x, a0);
            a1 = fmaf(trow[4*k+1], v.y, a1);
            a2 = fmaf(trow[4*k+2], v.z, a2);
            a3 = fmaf(trow[4*k+3], v.w, a3);
            s0 += v.x; s1 += v.y; s2 += v.z; s3 += v.w;
        }
        const float acc  = (a0 + a1) + (a2 + a3);
        const float ssum = (s0 + s1) + (s2 + s3);
        float val = fmaf(acc, g, bi);
        val = (ssum > 0.f) ? val : 0.f;

        // fold into LDS: row = t>>3, col = patch*8 + (t&7); 2-way banks (free)
        obuf[(lane >> 3) * OROW + (w << 3) + (lane & 7)] = val;
        __syncthreads();

        // ---- coalesced writeout: per wave one 256B contiguous aligned segment
        obase[(size_t)b * HW * HW + (size_t)orow * HW + ocol] = obuf[orow * OROW + ocol];

        // land next batch's src in the other buffer
        if (stager && (b + 1 < NB))
            *reinterpret_cast<float4*>(&sbuf[(b + 1) & 1][sdst]) = nv;
        __syncthreads();
    }
}

extern "C" void kernel_launch(void* const* d_in, const int* in_sizes, int n_in,
                              void* d_out, int out_size, void* d_ws, size_t ws_size,
                              hipStream_t stream) {
    const float* src    = (const float*)d_in[0];
    const float* tr     = (const float*)d_in[1];
    const float* gates  = (const float*)d_in[2];
    const float* biases = (const float*)d_in[3];
    float* out = (float*)d_out;

    dim3 grid(512);   // 64 ph * 8 pw-groups; exactly 2 blocks/CU
    dim3 block(512);  // 8 waves: wave = patch, lane = output row
    hipLaunchKernelGGL(axonal_kernel, grid, block, 0, stream,
                       src, tr, gates, biases, out);
}

// Round 3
// 37.805 us; speedup vs baseline: 12.6223x; 3.4572x over previous
//
#include <hip/hip_runtime.h>

#define HW 512

typedef __attribute__((ext_vector_type(4))) float f32x4;
typedef __attribute__((ext_vector_type(8))) short b16x8;
typedef __attribute__((ext_vector_type(4))) short b16x4;

__device__ __forceinline__ short f2bf(float f) {
    union { float f; unsigned u; } v; v.f = f;
    return (short)((v.u + 0x7FFFu + ((v.u >> 16) & 1u)) >> 16);  // RNE
}

__global__ __launch_bounds__(512, 4) void axonal_kernel(
    const float* __restrict__ src, const float* __restrict__ tr,
    const float* __restrict__ gates, const float* __restrict__ biases,
    float* __restrict__ out)
{
    const int gi  = blockIdx.x;
    const int ph  = gi >> 3;        // patch row 0..63
    const int pwg = gi & 7;         // group of 8 adjacent pw
    const int tid = threadIdx.x;
    const int w   = tid >> 6;       // wave = patch within group
    const int lane = tid & 63;
    const int lo  = lane & 15;
    const int hi  = lane >> 4;
    const int p   = (ph << 6) + (pwg << 3) + w;

    // pbuf: [16 b][8 p][64 s] bf16, batch stride 520 (1040B = 65 quads -> conflict-free A reads)
    __shared__ __align__(16) short pbuf[16 * 520];
    // obuf: [16 b][8 r][68] f32, batch stride 548 dwords (spreads quads)
    __shared__ __align__(16) float obuf[16 * 548];
    __shared__ __align__(16) float smask[128];   // [patch][local batch] strength

    // ---- B fragments (Tr[p] transposed), persistent in VGPRs, read once chip-wide.
    // mfma_f32_16x16x32_bf16 operand layout: elems 0-3 <- k = 4*hi + j,
    // elems 4-7 <- k = 16 + 4*hi + j (two K=16 halves); B col = lane&15.
    b16x8 bfr[8];  // [n*2 + ks]
    {
        const float* tp = tr + ((size_t)p << 12);
        #pragma unroll
        for (int n = 0; n < 4; ++n)
            #pragma unroll
            for (int ks = 0; ks < 2; ++ks) {
                const float* rp = tp + (n * 16 + lo) * 64 + ks * 32 + 4 * hi;
                float4 u0 = *reinterpret_cast<const float4*>(rp);
                float4 u1 = *reinterpret_cast<const float4*>(rp + 16);
                b16x8 v;
                v[0] = f2bf(u0.x); v[1] = f2bf(u0.y); v[2] = f2bf(u0.z); v[3] = f2bf(u0.w);
                v[4] = f2bf(u1.x); v[5] = f2bf(u1.y); v[6] = f2bf(u1.z); v[7] = f2bf(u1.w);
                bfr[n * 2 + ks] = v;
            }
    }
    const float g  = gates[p];
    const float bi = biases[p];

    // ---- staging map: thread -> (local batch sb, patch sp, row-pair ssub)
    const int sb   = tid >> 5;
    const int sp   = (tid >> 2) & 7;
    const int ssub = tid & 3;
    const float* sbase = src + (size_t)(ph * 8 + 2 * ssub) * HW + pwg * 64 + sp * 8;

    float4 ld0, ld1, ld2, ld3;
    {
        const float* q = sbase + (size_t)sb * HW * HW;
        ld0 = *reinterpret_cast<const float4*>(q);
        ld1 = *reinterpret_cast<const float4*>(q + 4);
        ld2 = *reinterpret_cast<const float4*>(q + HW);
        ld3 = *reinterpret_cast<const float4*>(q + HW + 4);
    }

    for (int c = 0; c < 4; ++c) {
        // ---- stage: exact f32 strength + bf16 LDS write
        float s = (ld0.x + ld0.y + ld0.z + ld0.w) + (ld1.x + ld1.y + ld1.z + ld1.w)
                + (ld2.x + ld2.y + ld2.z + ld2.w) + (ld3.x + ld3.y + ld3.z + ld3.w);
        s += __shfl_xor(s, 1);
        s += __shfl_xor(s, 2);
        if (ssub == 0) smask[sp * 16 + sb] = s;

        b16x8 w0, w1;
        w0[0] = f2bf(ld0.x); w0[1] = f2bf(ld0.y); w0[2] = f2bf(ld0.z); w0[3] = f2bf(ld0.w);
        w0[4] = f2bf(ld1.x); w0[5] = f2bf(ld1.y); w0[6] = f2bf(ld1.z); w0[7] = f2bf(ld1.w);
        w1[0] = f2bf(ld2.x); w1[1] = f2bf(ld2.y); w1[2] = f2bf(ld2.z); w1[3] = f2bf(ld2.w);
        w1[4] = f2bf(ld3.x); w1[5] = f2bf(ld3.y); w1[6] = f2bf(ld3.z); w1[7] = f2bf(ld3.w);
        short* dst = &pbuf[sb * 520 + sp * 64 + ssub * 16];
        *reinterpret_cast<b16x8*>(dst)     = w0;   // row 2*ssub
        *reinterpret_cast<b16x8*>(dst + 8) = w1;   // row 2*ssub+1
        __syncthreads();  // B1: pbuf + smask visible

        // ---- T14 prefetch next chunk (overlaps MFMA + epilogue + writeout)
        if (c < 3) {
            const float* q = sbase + (size_t)((c + 1) * 16 + sb) * HW * HW;
            ld0 = *reinterpret_cast<const float4*>(q);
            ld1 = *reinterpret_cast<const float4*>(q + 4);
            ld2 = *reinterpret_cast<const float4*>(q + HW);
            ld3 = *reinterpret_cast<const float4*>(q + HW + 4);
        }

        // ---- MFMA: C[16b x 64t] for patch w; A row = lane&15 (batch), same k layout as B
        f32x4 acc[4];
        acc[0] = (f32x4){0.f, 0.f, 0.f, 0.f};
        acc[1] = acc[0]; acc[2] = acc[0]; acc[3] = acc[0];
        #pragma unroll
        for (int ks = 0; ks < 2; ++ks) {
            const short* ap = &pbuf[lo * 520 + w * 64 + ks * 32 + 4 * hi];
            b16x4 a0 = *reinterpret_cast<const b16x4*>(ap);
            b16x4 a1 = *reinterpret_cast<const b16x4*>(ap + 16);
            b16x8 a;
            a[0] = a0[0]; a[1] = a0[1]; a[2] = a0[2]; a[3] = a0[3];
            a[4] = a1[0]; a[5] = a1[1]; a[6] = a1[2]; a[7] = a1[3];
            acc[0] = __builtin_amdgcn_mfma_f32_16x16x32_bf16(a, bfr[0 + ks], acc[0], 0, 0, 0);
            acc[1] = __builtin_amdgcn_mfma_f32_16x16x32_bf16(a, bfr[2 + ks], acc[1], 0, 0, 0);
            acc[2] = __builtin_amdgcn_mfma_f32_16x16x32_bf16(a, bfr[4 + ks], acc[2], 0, 0, 0);
            acc[3] = __builtin_amdgcn_mfma_f32_16x16x32_bf16(a, bfr[6 + ks], acc[3], 0, 0, 0);
        }

        // ---- epilogue: gate/bias/mask -> obuf. C/D: col=lane&15, row(b)=4*hi+reg (m89)
        f32x4 mk = *reinterpret_cast<const f32x4*>(&smask[w * 16 + 4 * hi]);
        #pragma unroll
        for (int n = 0; n < 4; ++n) {
            const int t = n * 16 + lo;
            float* ob = &obuf[(t >> 3) * 68 + w * 8 + (t & 7)];
            #pragma unroll
            for (int q = 0; q < 4; ++q) {
                float val = fmaf(acc[n][q], g, bi);
                val = (mk[q] > 0.f) ? val : 0.f;
                ob[(4 * hi + q) * 548] = val;
            }
        }
        __syncthreads();  // B3: obuf complete

        // ---- coalesced writeout: 256B contiguous segments
        #pragma unroll
        for (int i = 0; i < 4; ++i) {
            const int flat = i * 512 + tid;
            const int f4 = flat & 15, r = (flat >> 4) & 7, b = flat >> 7;
            float4 v = *reinterpret_cast<const float4*>(&obuf[b * 548 + r * 68 + f4 * 4]);
            *reinterpret_cast<float4*>(out + (size_t)(c * 16 + b) * HW * HW
                + (size_t)(ph * 8 + r) * HW + pwg * 64 + f4 * 4) = v;
        }
        // next chunk's stage (pbuf/smask writes) is ordered vs this chunk's reads by B3;
        // obuf rewrite is ordered by next B1.
    }
}

extern "C" void kernel_launch(void* const* d_in, const int* in_sizes, int n_in,
                              void* d_out, int out_size, void* d_ws, size_t ws_size,
                              hipStream_t stream) {
    const float* src    = (const float*)d_in[0];
    const float* tr     = (const float*)d_in[1];
    const float* gates  = (const float*)d_in[2];
    const float* biases = (const float*)d_in[3];
    float* out = (float*)d_out;

    dim3 grid(512);    // 64 ph * 8 pw-groups, 2 blocks/CU
    dim3 block(512);   // 8 waves, wave = patch
    hipLaunchKernelGGL(axonal_kernel, grid, block, 0, stream,
                       src, tr, gates, biases, out);
}